// Round 11
// baseline (558.004 us; speedup 1.0000x reference)
//
#include <hip/hip_runtime.h>
#include <hip/hip_cooperative_groups.h>
#include <math.h>

// GCN 2-layer (1->8->1), collapsed + factored + dst-binned (zero global atomics
// on the accumulate paths).
//
// Math (verified):
//   deg[d]  = #edges into d; dinv = rsqrt(deg+1)            (self-loop)
//   v[i]    = dinv[i]*x[i]                                  (stored fp16)
//   acc1[d] = sum_e v[src[e]]
//   at[i]   = dinv[i]*(acc1[i] + v[i])
//   u[i]    = dinv[i] * sum_j relu(at[i]*W1[j]+b1[j])*W2[j] (stored fp16)
//   out[d]  = dinv[d]*(acc2[d] + u[d]) + b2,  acc2[d] = sum_e u[src[e]]
//
// Round-11: (1) k_sort reverted to CHUNK=16384 (r10 proved it's DS-pipe /
// write-drain bound, not occupancy-bound: occ 17->36% made it SLOWER).
// (2) degv+gs1+gs2+finalize fused into ONE cooperative kernel (977 blocks x
// 512 thr, 16KB LDS -> 4 blocks/CU co-resident) with grid.sync between
// layers: saves 2 launches, keeps dinv/v_own/u_own in LDS, keeps each
// bucket's recs warm in its XCD L2 across phases.
// Record = ((dst&1023)<<20)|src (requires N <= 2^20; N = 1e6 here).

typedef int vint4 __attribute__((ext_vector_type(4)));

#define HB    1024    // bucket capacity in LDS tables (>= NB)
#define STHR  512     // sort block size (8 waves)
#define CHUNK 16384   // edges per sort block (best measured: r9)
#define BSH   10      // bucket shift (1024 nodes/bucket)
#define BMASK 1023

__global__ void k_zero_gcur(int* __restrict__ gcur, int NB) {
    int i = blockIdx.x * blockDim.x + threadIdx.x;
    if (i < NB) gcur[i] = 0;
}

// ---- fused counting sort: one block per 16K-edge chunk ----
__global__ __launch_bounds__(STHR) void k_sort(const int* __restrict__ src,
                                               const int* __restrict__ dst,
                                               int E, int NB, int C,
                                               int* __restrict__ gcur,
                                               int* __restrict__ recs) {
    __shared__ int cnt[HB];            // phase A: counts; phase C: cursors
    __shared__ int off[HB + 4];        // exclusive within-block offsets
    __shared__ int res[HB];            // res2[b] = C*b + gbase[b] - off[b]
    __shared__ int part[STHR];
    __shared__ int stage[CHUNK];       // 64 KB bucket-ordered record staging
    __shared__ unsigned short s2b[CHUNK]; // 32 KB slot -> bucket

    int t = threadIdx.x;
    for (int i = t; i < NB; i += STHR) cnt[i] = 0;
    __syncthreads();

    long s0 = (long)blockIdx.x * CHUNK;
    int end = (int)min((long)CHUNK, (long)E - s0);
    const vint4* pd = reinterpret_cast<const vint4*>(dst + s0);
    const vint4* ps = reinterpret_cast<const vint4*>(src + s0);
    int n4 = end >> 2;

    // ---- phase A: bucket histogram ----
    for (int k = t; k < n4; k += STHR) {
        vint4 d = __builtin_nontemporal_load(pd + k);
        atomicAdd(&cnt[((unsigned)d.x) >> BSH], 1);
        atomicAdd(&cnt[((unsigned)d.y) >> BSH], 1);
        atomicAdd(&cnt[((unsigned)d.z) >> BSH], 1);
        atomicAdd(&cnt[((unsigned)d.w) >> BSH], 1);
    }
    for (int k = (n4 << 2) + t; k < end; k += STHR)
        atomicAdd(&cnt[((unsigned)dst[s0 + k]) >> BSH], 1);
    __syncthreads();

    // ---- phase B: block scan (2 buckets/thread) + bulk global reservation ----
    int b0 = 2 * t, b1 = 2 * t + 1;
    int c0 = (b0 < NB) ? cnt[b0] : 0;
    int c1 = (b1 < NB) ? cnt[b1] : 0;
    part[t] = c0 + c1;
    __syncthreads();
    for (int o = 1; o < STHR; o <<= 1) {
        int pv = (t >= o) ? part[t - o] : 0;
        __syncthreads();
        part[t] += pv;
        __syncthreads();
    }
    int base0 = (t > 0) ? part[t - 1] : 0;
    if (b0 < NB) {
        off[b0] = base0;
        cnt[b0] = base0;                       // cursor for phase C
        int r0 = c0 ? atomicAdd(&gcur[b0], c0) : 0;
        res[b0] = b0 * C + r0 - base0;         // res2
    }
    if (b1 < NB) {
        int o1 = base0 + c0;
        off[b1] = o1;
        cnt[b1] = o1;
        int r1 = c1 ? atomicAdd(&gcur[b1], c1) : 0;
        res[b1] = b1 * C + r1 - o1;            // res2
    }
    __syncthreads();

    // ---- phase C: place records into LDS staging (bucket-ordered) ----
    for (int k = t; k < n4; k += STHR) {
        vint4 d = __builtin_nontemporal_load(pd + k);
        vint4 s = __builtin_nontemporal_load(ps + k);
        int b, slot;
        b = ((unsigned)d.x) >> BSH; slot = atomicAdd(&cnt[b], 1);
        stage[slot] = ((d.x & BMASK) << 20) | s.x; s2b[slot] = (unsigned short)b;
        b = ((unsigned)d.y) >> BSH; slot = atomicAdd(&cnt[b], 1);
        stage[slot] = ((d.y & BMASK) << 20) | s.y; s2b[slot] = (unsigned short)b;
        b = ((unsigned)d.z) >> BSH; slot = atomicAdd(&cnt[b], 1);
        stage[slot] = ((d.z & BMASK) << 20) | s.z; s2b[slot] = (unsigned short)b;
        b = ((unsigned)d.w) >> BSH; slot = atomicAdd(&cnt[b], 1);
        stage[slot] = ((d.w & BMASK) << 20) | s.w; s2b[slot] = (unsigned short)b;
    }
    for (int k = (n4 << 2) + t; k < end; k += STHR) {
        int d = dst[s0 + k], s = src[s0 + k];
        int b = ((unsigned)d) >> BSH;
        int slot = atomicAdd(&cnt[b], 1);
        stage[slot] = ((d & BMASK) << 20) | s;
        s2b[slot] = (unsigned short)b;
    }
    __syncthreads();

    // ---- phase D: coalesced flush, direct address ----
    for (int i = t; i < end; i += STHR) {
        int b = s2b[i];
        __builtin_nontemporal_store(stage[i], recs + (long)(res[b] + i));
    }
}

// ---- fused per-bucket layers: deg/dinv/v -> gridsync -> gs1 -> gridsync -> gs2 ----
__global__ __launch_bounds__(512) void k_layers(const int* __restrict__ recs,
                                                const int* __restrict__ gcur, int C,
                                                const float* __restrict__ x,
                                                const float* __restrict__ W1,
                                                const float* __restrict__ b1,
                                                const float* __restrict__ W2,
                                                const float* __restrict__ b2,
                                                _Float16* __restrict__ v,
                                                _Float16* __restrict__ u,
                                                float* __restrict__ out, int N) {
    namespace cg = cooperative_groups;
    cg::grid_group grid = cg::this_grid();

    __shared__ int   cnt[1024];      // phase-1 deg counts; reused as fp32 acc
    __shared__ float dinvs[1024];
    __shared__ float vown[1024];
    __shared__ float uown[1024];
    float* acc = (float*)cnt;

    int t = threadIdx.x;
    int b = blockIdx.x;
    long lo = (long)b * C;
    int m = gcur[b];
    const vint4* p = reinterpret_cast<const vint4*>(recs + lo);
    int n4 = m >> 2;

    // ---- phase 1: deg -> dinv, v ----
    cnt[t] = 0; cnt[t + 512] = 0;
    __syncthreads();
    for (int k = t; k < n4; k += 512) {
        vint4 r = __builtin_nontemporal_load(p + k);
        atomicAdd(&cnt[((unsigned)r.x) >> 20], 1);
        atomicAdd(&cnt[((unsigned)r.y) >> 20], 1);
        atomicAdd(&cnt[((unsigned)r.z) >> 20], 1);
        atomicAdd(&cnt[((unsigned)r.w) >> 20], 1);
    }
    for (int k = (n4 << 2) + t; k < m; k += 512)
        atomicAdd(&cnt[((unsigned)__builtin_nontemporal_load(recs + lo + k)) >> 20], 1);
    __syncthreads();
#pragma unroll
    for (int j = 0; j < 2; ++j) {
        int idx = t + 512 * j;
        int node = b * 1024 + idx;
        if (node < N) {
            float di = rsqrtf((float)cnt[idx] + 1.0f);
            float vv = di * x[node];
            dinvs[idx] = di;
            vown[idx] = vv;
            v[node] = (_Float16)vv;
        }
    }
    __syncthreads();                 // all cnt reads done before acc reuse
    acc[t] = 0.0f; acc[t + 512] = 0.0f;
    grid.sync();                     // v complete everywhere

    // ---- phase 2: gs1 (gather v[src], LDS scatter) + MLP -> u ----
    for (int k = t; k < n4; k += 512) {
        vint4 r = __builtin_nontemporal_load(p + k);
        float v0 = (float)v[r.x & 0xFFFFF], v1 = (float)v[r.y & 0xFFFFF];
        float v2 = (float)v[r.z & 0xFFFFF], v3 = (float)v[r.w & 0xFFFFF];
        atomicAdd(&acc[((unsigned)r.x) >> 20], v0);
        atomicAdd(&acc[((unsigned)r.y) >> 20], v1);
        atomicAdd(&acc[((unsigned)r.z) >> 20], v2);
        atomicAdd(&acc[((unsigned)r.w) >> 20], v3);
    }
    for (int k = (n4 << 2) + t; k < m; k += 512) {
        int r = __builtin_nontemporal_load(recs + lo + k);
        atomicAdd(&acc[((unsigned)r) >> 20], (float)v[r & 0xFFFFF]);
    }
    __syncthreads();
#pragma unroll
    for (int j = 0; j < 2; ++j) {
        int idx = t + 512 * j;
        int node = b * 1024 + idx;
        if (node < N) {
            float di = dinvs[idx];
            float at = di * (acc[idx] + vown[idx]);
            float s = 0.0f;
#pragma unroll
            for (int jj = 0; jj < 8; ++jj)
                s += fmaxf(at * W1[jj] + b1[jj], 0.0f) * W2[jj];
            float uu = di * s;
            uown[idx] = uu;
            u[node] = (_Float16)uu;
        }
    }
    __syncthreads();                 // acc reads done
    acc[t] = 0.0f; acc[t + 512] = 0.0f;
    grid.sync();                     // u complete everywhere

    // ---- phase 3: gs2 (gather u[src]) + finalize ----
    for (int k = t; k < n4; k += 512) {
        vint4 r = __builtin_nontemporal_load(p + k);
        float v0 = (float)u[r.x & 0xFFFFF], v1 = (float)u[r.y & 0xFFFFF];
        float v2 = (float)u[r.z & 0xFFFFF], v3 = (float)u[r.w & 0xFFFFF];
        atomicAdd(&acc[((unsigned)r.x) >> 20], v0);
        atomicAdd(&acc[((unsigned)r.y) >> 20], v1);
        atomicAdd(&acc[((unsigned)r.z) >> 20], v2);
        atomicAdd(&acc[((unsigned)r.w) >> 20], v3);
    }
    for (int k = (n4 << 2) + t; k < m; k += 512) {
        int r = __builtin_nontemporal_load(recs + lo + k);
        atomicAdd(&acc[((unsigned)r) >> 20], (float)u[r & 0xFFFFF]);
    }
    __syncthreads();
#pragma unroll
    for (int j = 0; j < 2; ++j) {
        int idx = t + 512 * j;
        int node = b * 1024 + idx;
        if (node < N)
            out[node] = dinvs[idx] * (acc[idx] + uown[idx]) + b2[0];
    }
}

extern "C" void kernel_launch(void* const* d_in, const int* in_sizes, int n_in,
                              void* d_out, int out_size, void* d_ws, size_t ws_size,
                              hipStream_t stream) {
    const float* x  = (const float*)d_in[0];
    const int*   ei = (const int*)d_in[1];   // [2, E] int32
    const float* W1 = (const float*)d_in[2];
    const float* b1 = (const float*)d_in[3];
    const float* W2 = (const float*)d_in[4];
    const float* b2 = (const float*)d_in[5];
    float* out = (float*)d_out;

    int N = in_sizes[0];
    int E = in_sizes[1] / 2;
    const int* src = ei;
    const int* dst = ei + E;

    int NB = (N + BMASK) >> BSH;             // 1024-node buckets (<= 1024 for N<=2^20)

    // fixed bucket capacity: avg + 8 sigma (Poisson), rounded to 64
    int avg = E / NB;
    int C = avg + 8 * (int)sqrt((double)avg) + 64;
    C = (C + 63) & ~63;
    size_t fixed = sizeof(_Float16) * 2ul * N + sizeof(int) * (size_t)NB;
    size_t maxC = (ws_size - fixed) / (sizeof(int) * (size_t)NB);
    if ((size_t)C > maxC) C = (int)maxC;

    char* w = (char*)d_ws;
    _Float16* v    = (_Float16*)w;  w += sizeof(_Float16) * (size_t)N;
    _Float16* u    = (_Float16*)w;  w += sizeof(_Float16) * (size_t)N;
    int*      gcur = (int*)w;       w += sizeof(int) * (size_t)NB;
    int*      recs = (int*)w;       // NB * C ints

    int NBLK = (E + CHUNK - 1) / CHUNK;

    k_zero_gcur<<<(NB + 255) / 256, 256, 0, stream>>>(gcur, NB);
    k_sort<<<NBLK, STHR, 0, stream>>>(src, dst, E, NB, C, gcur, recs);

    void* args[] = { (void*)&recs, (void*)&gcur, (void*)&C, (void*)&x,
                     (void*)&W1, (void*)&b1, (void*)&W2, (void*)&b2,
                     (void*)&v, (void*)&u, (void*)&out, (void*)&N };
    hipLaunchCooperativeKernel((const void*)k_layers, dim3(NB), dim3(512),
                               args, 0, stream);
}

// Round 12
// 295.626 us; speedup vs baseline: 1.8875x; 1.8875x over previous
//
#include <hip/hip_runtime.h>
#include <math.h>

// GCN 2-layer (1->8->1), collapsed + factored + dst-binned (zero global atomics
// on the accumulate paths).
//
// Math (verified):
//   deg[d]  = #edges into d; dinv = rsqrt(deg+1)            (self-loop)
//   v[i]    = dinv[i]*x[i]                                  (stored fp16)
//   acc1[d] = sum_e v[src[e]]
//   at[i]   = dinv[i]*(acc1[i] + v[i])
//   u[i]    = dinv[i] * sum_j relu(at[i]*W1[j]+b1[j])*W2[j] (stored fp16)
//   out[d]  = dinv[d]*(acc2[d] + u[d]) + b2,  acc2[d] = sum_e u[src[e]]
//
// Round-12: revert r11 fusion (cooperative kernel compiled at VGPR=12 ->
// serialized gathers, 346us). r9 structure + two k_sort write-amp changes:
// (1) phase-D store no longer NT (allow cross-block L2 write merging),
// (2) buckets 1024->2048 nodes (NB=489): ~33 rec/bucket/block = 134B runs.
// Record = ((dst&2047)<<20)|src (requires N <= 2^20; N = 1e6 here).

typedef int vint4 __attribute__((ext_vector_type(4)));

#define HB    512     // bucket table capacity (>= NB = 489)
#define STHR  512     // sort block size (8 waves)
#define CHUNK 16384   // edges per sort block (best measured: r9)
#define BSH   11      // bucket shift (2048 nodes/bucket)
#define BMASK 2047
#define NWIN  2048    // nodes per bucket window

__global__ void k_zero_gcur(int* __restrict__ gcur, int NB) {
    int i = blockIdx.x * blockDim.x + threadIdx.x;
    if (i < NB) gcur[i] = 0;
}

// ---- fused counting sort: one block per 16K-edge chunk ----
__global__ __launch_bounds__(STHR) void k_sort(const int* __restrict__ src,
                                               const int* __restrict__ dst,
                                               int E, int NB, int C,
                                               int* __restrict__ gcur,
                                               int* __restrict__ recs) {
    __shared__ int cnt[HB];            // phase A: counts; phase C: cursors
    __shared__ int off[HB + 4];        // exclusive within-block offsets
    __shared__ int res[HB];            // res2[b] = C*b + gbase[b] - off[b]
    __shared__ int part[STHR];
    __shared__ int stage[CHUNK];       // 64 KB bucket-ordered record staging
    __shared__ unsigned short s2b[CHUNK]; // 32 KB slot -> bucket

    int t = threadIdx.x;
    for (int i = t; i < NB; i += STHR) cnt[i] = 0;
    __syncthreads();

    long s0 = (long)blockIdx.x * CHUNK;
    int end = (int)min((long)CHUNK, (long)E - s0);
    const vint4* pd = reinterpret_cast<const vint4*>(dst + s0);
    const vint4* ps = reinterpret_cast<const vint4*>(src + s0);
    int n4 = end >> 2;

    // ---- phase A: bucket histogram ----
    for (int k = t; k < n4; k += STHR) {
        vint4 d = __builtin_nontemporal_load(pd + k);
        atomicAdd(&cnt[((unsigned)d.x) >> BSH], 1);
        atomicAdd(&cnt[((unsigned)d.y) >> BSH], 1);
        atomicAdd(&cnt[((unsigned)d.z) >> BSH], 1);
        atomicAdd(&cnt[((unsigned)d.w) >> BSH], 1);
    }
    for (int k = (n4 << 2) + t; k < end; k += STHR)
        atomicAdd(&cnt[((unsigned)dst[s0 + k]) >> BSH], 1);
    __syncthreads();

    // ---- phase B: block scan (1 bucket/thread; NB <= STHR) + reservation ----
    int c0 = (t < NB) ? cnt[t] : 0;
    part[t] = c0;
    __syncthreads();
    for (int o = 1; o < STHR; o <<= 1) {
        int pv = (t >= o) ? part[t - o] : 0;
        __syncthreads();
        part[t] += pv;
        __syncthreads();
    }
    int base0 = (t > 0) ? part[t - 1] : 0;
    if (t < NB) {
        off[t] = base0;
        cnt[t] = base0;                        // cursor for phase C
        int r0 = c0 ? atomicAdd(&gcur[t], c0) : 0;
        res[t] = t * C + r0 - base0;           // res2
    }
    __syncthreads();

    // ---- phase C: place records into LDS staging (bucket-ordered) ----
    for (int k = t; k < n4; k += STHR) {
        vint4 d = __builtin_nontemporal_load(pd + k);
        vint4 s = __builtin_nontemporal_load(ps + k);
        int b, slot;
        b = ((unsigned)d.x) >> BSH; slot = atomicAdd(&cnt[b], 1);
        stage[slot] = ((d.x & BMASK) << 20) | s.x; s2b[slot] = (unsigned short)b;
        b = ((unsigned)d.y) >> BSH; slot = atomicAdd(&cnt[b], 1);
        stage[slot] = ((d.y & BMASK) << 20) | s.y; s2b[slot] = (unsigned short)b;
        b = ((unsigned)d.z) >> BSH; slot = atomicAdd(&cnt[b], 1);
        stage[slot] = ((d.z & BMASK) << 20) | s.z; s2b[slot] = (unsigned short)b;
        b = ((unsigned)d.w) >> BSH; slot = atomicAdd(&cnt[b], 1);
        stage[slot] = ((d.w & BMASK) << 20) | s.w; s2b[slot] = (unsigned short)b;
    }
    for (int k = (n4 << 2) + t; k < end; k += STHR) {
        int d = dst[s0 + k], s = src[s0 + k];
        int b = ((unsigned)d) >> BSH;
        int slot = atomicAdd(&cnt[b], 1);
        stage[slot] = ((d & BMASK) << 20) | s;
        s2b[slot] = (unsigned short)b;
    }
    __syncthreads();

    // ---- phase D: flush; plain store so L2 can merge partial lines ----
    for (int i = t; i < end; i += STHR) {
        int b = s2b[i];
        recs[(long)(res[b] + i)] = stage[i];
    }
}

// ---- per-bucket deg count -> dinv, v(fp16) ----
__global__ __launch_bounds__(512) void k_degv(const int* __restrict__ recs,
                                              const int* __restrict__ gcur, int C,
                                              const float* __restrict__ x,
                                              float* __restrict__ dinv,
                                              _Float16* __restrict__ v, int N) {
    __shared__ int c[NWIN];
    int t = threadIdx.x;
#pragma unroll
    for (int j = 0; j < NWIN / 512; ++j) c[t + 512 * j] = 0;
    __syncthreads();
    long lo = (long)blockIdx.x * C;
    int cnt_ = gcur[blockIdx.x];
    int n4 = cnt_ >> 2;
    const vint4* p = reinterpret_cast<const vint4*>(recs + lo);
    for (int k = t; k < n4; k += 512) {
        vint4 r = __builtin_nontemporal_load(p + k);
        atomicAdd(&c[((unsigned)r.x) >> 20], 1);
        atomicAdd(&c[((unsigned)r.y) >> 20], 1);
        atomicAdd(&c[((unsigned)r.z) >> 20], 1);
        atomicAdd(&c[((unsigned)r.w) >> 20], 1);
    }
    for (int k = (n4 << 2) + t; k < cnt_; k += 512)
        atomicAdd(&c[((unsigned)__builtin_nontemporal_load(recs + lo + k)) >> 20], 1);
    __syncthreads();
#pragma unroll
    for (int j = 0; j < NWIN / 512; ++j) {
        int idx = t + 512 * j;
        int node = blockIdx.x * NWIN + idx;
        if (node < N) {
            float di = rsqrtf((float)c[idx] + 1.0f);
            dinv[node] = di;
            v[node] = (_Float16)(di * x[node]);
        }
    }
}

// ---- layer-1 gather/LDS-scatter + fused MLP -> u(fp16) ----
__global__ __launch_bounds__(512) void k_gs1(const int* __restrict__ recs,
                                             const int* __restrict__ gcur, int C,
                                             const _Float16* __restrict__ v,
                                             const float* __restrict__ dinv,
                                             const float* __restrict__ W1,
                                             const float* __restrict__ b1,
                                             const float* __restrict__ W2,
                                             _Float16* __restrict__ u, int N) {
    __shared__ float acc[NWIN];
    int t = threadIdx.x;
#pragma unroll
    for (int j = 0; j < NWIN / 512; ++j) acc[t + 512 * j] = 0.0f;
    __syncthreads();
    long lo = (long)blockIdx.x * C;
    int cnt_ = gcur[blockIdx.x];
    int n4 = cnt_ >> 2;
    const vint4* p = reinterpret_cast<const vint4*>(recs + lo);
    for (int k = t; k < n4; k += 512) {
        vint4 r = __builtin_nontemporal_load(p + k);
        float v0 = (float)v[r.x & 0xFFFFF], v1 = (float)v[r.y & 0xFFFFF];
        float v2 = (float)v[r.z & 0xFFFFF], v3 = (float)v[r.w & 0xFFFFF];
        atomicAdd(&acc[((unsigned)r.x) >> 20], v0);
        atomicAdd(&acc[((unsigned)r.y) >> 20], v1);
        atomicAdd(&acc[((unsigned)r.z) >> 20], v2);
        atomicAdd(&acc[((unsigned)r.w) >> 20], v3);
    }
    for (int k = (n4 << 2) + t; k < cnt_; k += 512) {
        int r = __builtin_nontemporal_load(recs + lo + k);
        atomicAdd(&acc[((unsigned)r) >> 20], (float)v[r & 0xFFFFF]);
    }
    __syncthreads();
#pragma unroll
    for (int j = 0; j < NWIN / 512; ++j) {
        int idx = t + 512 * j;
        int node = blockIdx.x * NWIN + idx;
        if (node < N) {
            float di = dinv[node];
            float at = di * (acc[idx] + (float)v[node]);
            float s = 0.0f;
#pragma unroll
            for (int jj = 0; jj < 8; ++jj)
                s += fmaxf(at * W1[jj] + b1[jj], 0.0f) * W2[jj];
            u[node] = (_Float16)(di * s);
        }
    }
}

// ---- layer-2 gather/LDS-scatter + fused finalize -> out ----
__global__ __launch_bounds__(512) void k_gs2(const int* __restrict__ recs,
                                             const int* __restrict__ gcur, int C,
                                             const _Float16* __restrict__ u,
                                             const float* __restrict__ dinv,
                                             const float* __restrict__ b2,
                                             float* __restrict__ out, int N) {
    __shared__ float acc[NWIN];
    int t = threadIdx.x;
#pragma unroll
    for (int j = 0; j < NWIN / 512; ++j) acc[t + 512 * j] = 0.0f;
    __syncthreads();
    long lo = (long)blockIdx.x * C;
    int cnt_ = gcur[blockIdx.x];
    int n4 = cnt_ >> 2;
    const vint4* p = reinterpret_cast<const vint4*>(recs + lo);
    for (int k = t; k < n4; k += 512) {
        vint4 r = __builtin_nontemporal_load(p + k);
        float v0 = (float)u[r.x & 0xFFFFF], v1 = (float)u[r.y & 0xFFFFF];
        float v2 = (float)u[r.z & 0xFFFFF], v3 = (float)u[r.w & 0xFFFFF];
        atomicAdd(&acc[((unsigned)r.x) >> 20], v0);
        atomicAdd(&acc[((unsigned)r.y) >> 20], v1);
        atomicAdd(&acc[((unsigned)r.z) >> 20], v2);
        atomicAdd(&acc[((unsigned)r.w) >> 20], v3);
    }
    for (int k = (n4 << 2) + t; k < cnt_; k += 512) {
        int r = __builtin_nontemporal_load(recs + lo + k);
        atomicAdd(&acc[((unsigned)r) >> 20], (float)u[r & 0xFFFFF]);
    }
    __syncthreads();
#pragma unroll
    for (int j = 0; j < NWIN / 512; ++j) {
        int idx = t + 512 * j;
        int node = blockIdx.x * NWIN + idx;
        if (node < N)
            out[node] = dinv[node] * (acc[idx] + (float)u[node]) + b2[0];
    }
}

extern "C" void kernel_launch(void* const* d_in, const int* in_sizes, int n_in,
                              void* d_out, int out_size, void* d_ws, size_t ws_size,
                              hipStream_t stream) {
    const float* x  = (const float*)d_in[0];
    const int*   ei = (const int*)d_in[1];   // [2, E] int32
    const float* W1 = (const float*)d_in[2];
    const float* b1 = (const float*)d_in[3];
    const float* W2 = (const float*)d_in[4];
    const float* b2 = (const float*)d_in[5];
    float* out = (float*)d_out;

    int N = in_sizes[0];
    int E = in_sizes[1] / 2;
    const int* src = ei;
    const int* dst = ei + E;

    int NB = (N + BMASK) >> BSH;             // 2048-node buckets (489 for N=1e6)

    // fixed bucket capacity: avg + 8 sigma (Poisson), rounded to 64
    int avg = E / NB;
    int C = avg + 8 * (int)sqrt((double)avg) + 64;
    C = (C + 63) & ~63;
    size_t fixed = sizeof(float) * (size_t)N + sizeof(_Float16) * 2ul * N
                 + sizeof(int) * (size_t)NB;
    size_t maxC = (ws_size - fixed) / (sizeof(int) * (size_t)NB);
    if ((size_t)C > maxC) C = (int)maxC;

    char* w = (char*)d_ws;
    float*    dinv = (float*)w;     w += sizeof(float) * (size_t)N;
    _Float16* v    = (_Float16*)w;  w += sizeof(_Float16) * (size_t)N;
    _Float16* u    = (_Float16*)w;  w += sizeof(_Float16) * (size_t)N;
    int*      gcur = (int*)w;       w += sizeof(int) * (size_t)NB;
    int*      recs = (int*)w;       // NB * C ints

    int NBLK = (E + CHUNK - 1) / CHUNK;

    k_zero_gcur<<<(NB + 255) / 256, 256, 0, stream>>>(gcur, NB);
    k_sort<<<NBLK, STHR, 0, stream>>>(src, dst, E, NB, C, gcur, recs);
    k_degv<<<NB, 512, 0, stream>>>(recs, gcur, C, x, dinv, v, N);
    k_gs1 <<<NB, 512, 0, stream>>>(recs, gcur, C, v, dinv, W1, b1, W2, u, N);
    k_gs2 <<<NB, 512, 0, stream>>>(recs, gcur, C, u, dinv, b2, out, N);
}

// Round 13
// 281.160 us; speedup vs baseline: 1.9846x; 1.0515x over previous
//
#include <hip/hip_runtime.h>
#include <math.h>

// GCN 2-layer (1->8->1), collapsed + factored + dst-binned (zero global atomics
// on the accumulate paths).
//
// Math (verified):
//   deg[d]  = #edges into d; dinv = rsqrt(deg+1)            (self-loop)
//   v[i]    = dinv[i]*x[i]                                  (stored fp16)
//   acc1[d] = sum_e v[src[e]]
//   at[i]   = dinv[i]*(acc1[i] + v[i])
//   u[i]    = dinv[i] * sum_j relu(at[i]*W1[j]+b1[j])*W2[j] (stored fp16)
//   out[d]  = dinv[d]*(acc2[d] + u[d]) + b2,  acc2[d] = sum_e u[src[e]]
//
// Round-13: r12 showed VGPR_Count=12 on the bucket passes -> serialized
// load/gather chains (same codegen pathology that sank r11's fusion).
// Fix: DUAL independent iteration streams per thread (forces 2 record-quads
// + 8 gathers live -> real MLP). k_sort: STHR 512->1024 (same CHUNK; tests
// waves without r10's write-amp confound), phase-A dst load non-NT so the
// phase-C re-read hits L2.
// Record = ((dst&2047)<<20)|src (requires N <= 2^20; N = 1e6 here).

typedef int vint4 __attribute__((ext_vector_type(4)));

#define HB    512     // bucket table capacity (>= NB = 489)
#define STHR  1024    // sort block size (16 waves)
#define CHUNK 16384   // edges per sort block
#define BSH   11      // bucket shift (2048 nodes/bucket)
#define BMASK 2047
#define NWIN  2048    // nodes per bucket window

__global__ void k_zero_gcur(int* __restrict__ gcur, int NB) {
    int i = blockIdx.x * blockDim.x + threadIdx.x;
    if (i < NB) gcur[i] = 0;
}

// ---- fused counting sort: one block per 16K-edge chunk ----
__global__ __launch_bounds__(STHR) void k_sort(const int* __restrict__ src,
                                               const int* __restrict__ dst,
                                               int E, int NB, int C,
                                               int* __restrict__ gcur,
                                               int* __restrict__ recs) {
    __shared__ int cnt[HB];            // phase A: counts; phase C: cursors
    __shared__ int off[HB + 4];        // exclusive within-block offsets
    __shared__ int res[HB];            // res2[b] = C*b + gbase[b] - off[b]
    __shared__ int part[STHR];
    __shared__ int stage[CHUNK];       // 64 KB bucket-ordered record staging
    __shared__ unsigned short s2b[CHUNK]; // 32 KB slot -> bucket

    int t = threadIdx.x;
    for (int i = t; i < NB; i += STHR) cnt[i] = 0;
    __syncthreads();

    long s0 = (long)blockIdx.x * CHUNK;
    int end = (int)min((long)CHUNK, (long)E - s0);
    const vint4* pd = reinterpret_cast<const vint4*>(dst + s0);
    const vint4* ps = reinterpret_cast<const vint4*>(src + s0);
    int n4 = end >> 2;

    // ---- phase A: bucket histogram (plain load: keep dst lines in L2 for C) ----
    for (int k = t; k < n4; k += STHR) {
        vint4 d = pd[k];
        atomicAdd(&cnt[((unsigned)d.x) >> BSH], 1);
        atomicAdd(&cnt[((unsigned)d.y) >> BSH], 1);
        atomicAdd(&cnt[((unsigned)d.z) >> BSH], 1);
        atomicAdd(&cnt[((unsigned)d.w) >> BSH], 1);
    }
    for (int k = (n4 << 2) + t; k < end; k += STHR)
        atomicAdd(&cnt[((unsigned)dst[s0 + k]) >> BSH], 1);
    __syncthreads();

    // ---- phase B: block scan (1 bucket/thread; NB <= STHR) + reservation ----
    int c0 = (t < NB) ? cnt[t] : 0;
    part[t] = c0;
    __syncthreads();
    for (int o = 1; o < STHR; o <<= 1) {
        int pv = (t >= o) ? part[t - o] : 0;
        __syncthreads();
        part[t] += pv;
        __syncthreads();
    }
    int base0 = (t > 0) ? part[t - 1] : 0;
    if (t < NB) {
        off[t] = base0;
        cnt[t] = base0;                        // cursor for phase C
        int r0 = c0 ? atomicAdd(&gcur[t], c0) : 0;
        res[t] = t * C + r0 - base0;           // res2
    }
    __syncthreads();

    // ---- phase C: place records into LDS staging (bucket-ordered) ----
    for (int k = t; k < n4; k += STHR) {
        vint4 d = pd[k];
        vint4 s = __builtin_nontemporal_load(ps + k);
        int b, slot;
        b = ((unsigned)d.x) >> BSH; slot = atomicAdd(&cnt[b], 1);
        stage[slot] = ((d.x & BMASK) << 20) | s.x; s2b[slot] = (unsigned short)b;
        b = ((unsigned)d.y) >> BSH; slot = atomicAdd(&cnt[b], 1);
        stage[slot] = ((d.y & BMASK) << 20) | s.y; s2b[slot] = (unsigned short)b;
        b = ((unsigned)d.z) >> BSH; slot = atomicAdd(&cnt[b], 1);
        stage[slot] = ((d.z & BMASK) << 20) | s.z; s2b[slot] = (unsigned short)b;
        b = ((unsigned)d.w) >> BSH; slot = atomicAdd(&cnt[b], 1);
        stage[slot] = ((d.w & BMASK) << 20) | s.w; s2b[slot] = (unsigned short)b;
    }
    for (int k = (n4 << 2) + t; k < end; k += STHR) {
        int d = dst[s0 + k], s = src[s0 + k];
        int b = ((unsigned)d) >> BSH;
        int slot = atomicAdd(&cnt[b], 1);
        stage[slot] = ((d & BMASK) << 20) | s;
        s2b[slot] = (unsigned short)b;
    }
    __syncthreads();

    // ---- phase D: flush; plain store so L2 can merge partial lines ----
    for (int i = t; i < end; i += STHR) {
        int b = s2b[i];
        recs[(long)(res[b] + i)] = stage[i];
    }
}

// ---- per-bucket deg count -> dinv, v(fp16); dual-stream for MLP ----
__global__ __launch_bounds__(512) void k_degv(const int* __restrict__ recs,
                                              const int* __restrict__ gcur, int C,
                                              const float* __restrict__ x,
                                              float* __restrict__ dinv,
                                              _Float16* __restrict__ v, int N) {
    __shared__ int c[NWIN];
    int t = threadIdx.x;
#pragma unroll
    for (int j = 0; j < NWIN / 512; ++j) c[t + 512 * j] = 0;
    __syncthreads();
    long lo = (long)blockIdx.x * C;
    int cnt_ = gcur[blockIdx.x];
    int n4 = cnt_ >> 2;
    const vint4* p = reinterpret_cast<const vint4*>(recs + lo);
    int h4 = (n4 + 1) >> 1;
    for (int k = t; k < h4; k += 512) {
        vint4 ra = __builtin_nontemporal_load(p + k);
        int kb = k + h4;
        bool hb = kb < n4;
        vint4 rb = hb ? __builtin_nontemporal_load(p + kb) : ra;
        atomicAdd(&c[((unsigned)ra.x) >> 20], 1);
        atomicAdd(&c[((unsigned)ra.y) >> 20], 1);
        atomicAdd(&c[((unsigned)ra.z) >> 20], 1);
        atomicAdd(&c[((unsigned)ra.w) >> 20], 1);
        if (hb) {
            atomicAdd(&c[((unsigned)rb.x) >> 20], 1);
            atomicAdd(&c[((unsigned)rb.y) >> 20], 1);
            atomicAdd(&c[((unsigned)rb.z) >> 20], 1);
            atomicAdd(&c[((unsigned)rb.w) >> 20], 1);
        }
    }
    for (int k = (n4 << 2) + t; k < cnt_; k += 512)
        atomicAdd(&c[((unsigned)__builtin_nontemporal_load(recs + lo + k)) >> 20], 1);
    __syncthreads();
#pragma unroll
    for (int j = 0; j < NWIN / 512; ++j) {
        int idx = t + 512 * j;
        int node = blockIdx.x * NWIN + idx;
        if (node < N) {
            float di = rsqrtf((float)c[idx] + 1.0f);
            dinv[node] = di;
            v[node] = (_Float16)(di * x[node]);
        }
    }
}

// ---- layer-1 gather/LDS-scatter + fused MLP -> u(fp16); dual-stream ----
__global__ __launch_bounds__(512) void k_gs1(const int* __restrict__ recs,
                                             const int* __restrict__ gcur, int C,
                                             const _Float16* __restrict__ v,
                                             const float* __restrict__ dinv,
                                             const float* __restrict__ W1,
                                             const float* __restrict__ b1,
                                             const float* __restrict__ W2,
                                             _Float16* __restrict__ u, int N) {
    __shared__ float acc[NWIN];
    int t = threadIdx.x;
#pragma unroll
    for (int j = 0; j < NWIN / 512; ++j) acc[t + 512 * j] = 0.0f;
    __syncthreads();
    long lo = (long)blockIdx.x * C;
    int cnt_ = gcur[blockIdx.x];
    int n4 = cnt_ >> 2;
    const vint4* p = reinterpret_cast<const vint4*>(recs + lo);
    int h4 = (n4 + 1) >> 1;
    for (int k = t; k < h4; k += 512) {
        vint4 ra = __builtin_nontemporal_load(p + k);
        int kb = k + h4;
        bool hb = kb < n4;
        vint4 rb = hb ? __builtin_nontemporal_load(p + kb) : ra;
        float a0 = (float)v[ra.x & 0xFFFFF], a1 = (float)v[ra.y & 0xFFFFF];
        float a2 = (float)v[ra.z & 0xFFFFF], a3 = (float)v[ra.w & 0xFFFFF];
        float g0 = (float)v[rb.x & 0xFFFFF], g1 = (float)v[rb.y & 0xFFFFF];
        float g2 = (float)v[rb.z & 0xFFFFF], g3 = (float)v[rb.w & 0xFFFFF];
        atomicAdd(&acc[((unsigned)ra.x) >> 20], a0);
        atomicAdd(&acc[((unsigned)ra.y) >> 20], a1);
        atomicAdd(&acc[((unsigned)ra.z) >> 20], a2);
        atomicAdd(&acc[((unsigned)ra.w) >> 20], a3);
        if (hb) {
            atomicAdd(&acc[((unsigned)rb.x) >> 20], g0);
            atomicAdd(&acc[((unsigned)rb.y) >> 20], g1);
            atomicAdd(&acc[((unsigned)rb.z) >> 20], g2);
            atomicAdd(&acc[((unsigned)rb.w) >> 20], g3);
        }
    }
    for (int k = (n4 << 2) + t; k < cnt_; k += 512) {
        int r = __builtin_nontemporal_load(recs + lo + k);
        atomicAdd(&acc[((unsigned)r) >> 20], (float)v[r & 0xFFFFF]);
    }
    __syncthreads();
#pragma unroll
    for (int j = 0; j < NWIN / 512; ++j) {
        int idx = t + 512 * j;
        int node = blockIdx.x * NWIN + idx;
        if (node < N) {
            float di = dinv[node];
            float at = di * (acc[idx] + (float)v[node]);
            float s = 0.0f;
#pragma unroll
            for (int jj = 0; jj < 8; ++jj)
                s += fmaxf(at * W1[jj] + b1[jj], 0.0f) * W2[jj];
            u[node] = (_Float16)(di * s);
        }
    }
}

// ---- layer-2 gather/LDS-scatter + fused finalize -> out; dual-stream ----
__global__ __launch_bounds__(512) void k_gs2(const int* __restrict__ recs,
                                             const int* __restrict__ gcur, int C,
                                             const _Float16* __restrict__ u,
                                             const float* __restrict__ dinv,
                                             const float* __restrict__ b2,
                                             float* __restrict__ out, int N) {
    __shared__ float acc[NWIN];
    int t = threadIdx.x;
#pragma unroll
    for (int j = 0; j < NWIN / 512; ++j) acc[t + 512 * j] = 0.0f;
    __syncthreads();
    long lo = (long)blockIdx.x * C;
    int cnt_ = gcur[blockIdx.x];
    int n4 = cnt_ >> 2;
    const vint4* p = reinterpret_cast<const vint4*>(recs + lo);
    int h4 = (n4 + 1) >> 1;
    for (int k = t; k < h4; k += 512) {
        vint4 ra = __builtin_nontemporal_load(p + k);
        int kb = k + h4;
        bool hb = kb < n4;
        vint4 rb = hb ? __builtin_nontemporal_load(p + kb) : ra;
        float a0 = (float)u[ra.x & 0xFFFFF], a1 = (float)u[ra.y & 0xFFFFF];
        float a2 = (float)u[ra.z & 0xFFFFF], a3 = (float)u[ra.w & 0xFFFFF];
        float g0 = (float)u[rb.x & 0xFFFFF], g1 = (float)u[rb.y & 0xFFFFF];
        float g2 = (float)u[rb.z & 0xFFFFF], g3 = (float)u[rb.w & 0xFFFFF];
        atomicAdd(&acc[((unsigned)ra.x) >> 20], a0);
        atomicAdd(&acc[((unsigned)ra.y) >> 20], a1);
        atomicAdd(&acc[((unsigned)ra.z) >> 20], a2);
        atomicAdd(&acc[((unsigned)ra.w) >> 20], a3);
        if (hb) {
            atomicAdd(&acc[((unsigned)rb.x) >> 20], g0);
            atomicAdd(&acc[((unsigned)rb.y) >> 20], g1);
            atomicAdd(&acc[((unsigned)rb.z) >> 20], g2);
            atomicAdd(&acc[((unsigned)rb.w) >> 20], g3);
        }
    }
    for (int k = (n4 << 2) + t; k < cnt_; k += 512) {
        int r = __builtin_nontemporal_load(recs + lo + k);
        atomicAdd(&acc[((unsigned)r) >> 20], (float)u[r & 0xFFFFF]);
    }
    __syncthreads();
#pragma unroll
    for (int j = 0; j < NWIN / 512; ++j) {
        int idx = t + 512 * j;
        int node = blockIdx.x * NWIN + idx;
        if (node < N)
            out[node] = dinv[node] * (acc[idx] + (float)u[node]) + b2[0];
    }
}

extern "C" void kernel_launch(void* const* d_in, const int* in_sizes, int n_in,
                              void* d_out, int out_size, void* d_ws, size_t ws_size,
                              hipStream_t stream) {
    const float* x  = (const float*)d_in[0];
    const int*   ei = (const int*)d_in[1];   // [2, E] int32
    const float* W1 = (const float*)d_in[2];
    const float* b1 = (const float*)d_in[3];
    const float* W2 = (const float*)d_in[4];
    const float* b2 = (const float*)d_in[5];
    float* out = (float*)d_out;

    int N = in_sizes[0];
    int E = in_sizes[1] / 2;
    const int* src = ei;
    const int* dst = ei + E;

    int NB = (N + BMASK) >> BSH;             // 2048-node buckets (489 for N=1e6)

    // fixed bucket capacity: avg + 8 sigma (Poisson), rounded to 64
    int avg = E / NB;
    int C = avg + 8 * (int)sqrt((double)avg) + 64;
    C = (C + 63) & ~63;
    size_t fixed = sizeof(float) * (size_t)N + sizeof(_Float16) * 2ul * N
                 + sizeof(int) * (size_t)NB;
    size_t maxC = (ws_size - fixed) / (sizeof(int) * (size_t)NB);
    if ((size_t)C > maxC) C = (int)maxC;

    char* w = (char*)d_ws;
    float*    dinv = (float*)w;     w += sizeof(float) * (size_t)N;
    _Float16* v    = (_Float16*)w;  w += sizeof(_Float16) * (size_t)N;
    _Float16* u    = (_Float16*)w;  w += sizeof(_Float16) * (size_t)N;
    int*      gcur = (int*)w;       w += sizeof(int) * (size_t)NB;
    int*      recs = (int*)w;       // NB * C ints

    int NBLK = (E + CHUNK - 1) / CHUNK;

    k_zero_gcur<<<(NB + 255) / 256, 256, 0, stream>>>(gcur, NB);
    k_sort<<<NBLK, STHR, 0, stream>>>(src, dst, E, NB, C, gcur, recs);
    k_degv<<<NB, 512, 0, stream>>>(recs, gcur, C, x, dinv, v, N);
    k_gs1 <<<NB, 512, 0, stream>>>(recs, gcur, C, v, dinv, W1, b1, W2, u, N);
    k_gs2 <<<NB, 512, 0, stream>>>(recs, gcur, C, u, dinv, b2, out, N);
}